// Round 10
// baseline (347.754 us; speedup 1.0000x reference)
//
#include <hip/hip_runtime.h>
#include <hip/hip_bf16.h>
#include <math.h>

#define Bz 131072
#define Dd 256

typedef __attribute__((ext_vector_type(8))) short short8;
typedef __attribute__((ext_vector_type(4))) float f32x4;
typedef __attribute__((ext_vector_type(4))) unsigned short u16x4;
typedef __attribute__((ext_vector_type(8))) unsigned short u16x8;

__device__ __forceinline__ unsigned short f2bf(float f) {
    union { float f; unsigned int u; } v; v.f = f;
    unsigned int r = v.u + 0x7FFFu + ((v.u >> 16) & 1u);   // RNE
    return (unsigned short)(r >> 16);
}
__device__ __forceinline__ float bf2f(unsigned short h) {
    union { unsigned int u; float f; } v; v.u = ((unsigned int)h) << 16;
    return v.f;
}
// tanh-form gelu: 0.5x(1+tanh(0.7978845608(x+0.044715x^3))), tanh via v_exp_f32 (2^x)
__device__ __forceinline__ float gelu_f(float x) {
    float u = 0.7978845608028654f * x * (1.0f + 0.044715f * x * x);
    float ex = __builtin_amdgcn_exp2f(u * 2.8853900817779268f);  // 2*log2(e)
    float th = 1.0f - 2.0f * __builtin_amdgcn_rcpf(1.0f + ex);
    return 0.5f * x * (1.0f + th);
}

__device__ __forceinline__ void gload_lds16(const unsigned short* g, char* l) {
    __builtin_amdgcn_global_load_lds(
        (const __attribute__((address_space(1))) unsigned int*)g,
        (__attribute__((address_space(3))) unsigned int*)l, 16, 0, 0);
}

#define MFMA16(a, b, c) __builtin_amdgcn_mfma_f32_16x16x32_bf16(a, b, c, 0, 0, 0)
#define SWZ(row) (((row) & 15) << 5)
#define VMCNT2 asm volatile("s_waitcnt vmcnt(2)" ::: "memory")
#define VMCNT0 asm volatile("s_waitcnt vmcnt(0)" ::: "memory")
#define LGK0   asm volatile("s_waitcnt lgkmcnt(0)" ::: "memory")
#define BARRAW __builtin_amdgcn_s_barrier
#define SCHED0() __builtin_amdgcn_sched_barrier(0)

// ctr layout (uint): [0..3] expert counts, [4..9] pair hist, [10..15] cursors, [16..22] bases
// ---------- prep: transpose weights to k-contiguous bf16; zero counters
__global__ __launch_bounds__(256) void prep_kernel(const float* __restrict__ W1,
                                                   const float* __restrict__ W2,
                                                   unsigned short* __restrict__ W1t,
                                                   unsigned short* __restrict__ W2t,
                                                   unsigned int* __restrict__ ctr) {
    int idx = blockIdx.x * 256 + threadIdx.x;          // 0 .. 262143
    if (idx < 16) ctr[idx] = 0u;
    int e = idx >> 16, a = (idx >> 8) & 255, b = idx & 255;
    int src = (e << 16) + (b << 8) + a;                // out[e][a][b] = in[e][b][a]
    W1t[idx] = f2bf(W1[src]);
    W2t[idx] = f2bf(W2[src]);
}

// ---------- gate: f64 distances -> top-2 -> weights + pair histogram + counts
__global__ __launch_bounds__(256) void gate_kernel(const float* __restrict__ z,
                                                   const int* __restrict__ ridx_p,
                                                   const float* __restrict__ centroids,
                                                   const float* __restrict__ tau_raw,
                                                   float* __restrict__ wdense,
                                                   unsigned int* __restrict__ ctr) {
    __shared__ unsigned int scnt[4];
    __shared__ unsigned int shist[6];
    int tid = threadIdx.x;
    if (tid < 4) scnt[tid] = 0u;
    if (tid < 6) shist[tid] = 0u;
    __syncthreads();
    int lane = tid & 63;
    int gwave = (blockIdx.x * 256 + tid) >> 6;         // 16 rows each
    int ridx = ridx_p[0];
    double tau = log1p(exp((double)tau_raw[ridx])) + 1e-6;
    const float* cb = centroids + (size_t)ridx * (4 * Dd);
    float c[4][4];
#pragma unroll
    for (int e = 0; e < 4; ++e) {
        f32x4 cv = *(const f32x4*)(cb + e * 256 + lane * 4);
#pragma unroll
        for (int j = 0; j < 4; ++j) c[e][j] = cv[j];
    }
    for (int rr = 0; rr < 16; ++rr) {
        int row = gwave * 16 + rr;
        f32x4 zv = *(const f32x4*)(z + (size_t)row * 256 + lane * 4);
        double d2[4] = {0.0, 0.0, 0.0, 0.0};
#pragma unroll
        for (int e = 0; e < 4; ++e)
#pragma unroll
            for (int j = 0; j < 4; ++j) {
                double df = (double)zv[j] - (double)c[e][j];
                d2[e] += df * df;
            }
#pragma unroll
        for (int m = 32; m >= 1; m >>= 1)
#pragma unroll
            for (int e = 0; e < 4; ++e) d2[e] += __shfl_xor(d2[e], m, 64);
        if (lane == 0) {
            int e1 = 0;
#pragma unroll
            for (int e = 1; e < 4; ++e) if (d2[e] < d2[e1]) e1 = e;
            int e2 = (e1 == 0) ? 1 : 0;
#pragma unroll
            for (int e = 0; e < 4; ++e)
                if (e != e1 && e != e2 && d2[e] < d2[e2]) e2 = e;
            double s1 = exp(-sqrt(d2[e1]) / tau);
            double s2 = exp(-sqrt(d2[e2]) / tau);
            double w1 = 1.0 / (1.0 + exp(s2 - s1));
            f32x4 wv;
#pragma unroll
            for (int j = 0; j < 4; ++j)
                wv[j] = (j == e1) ? (float)w1 : ((j == e2) ? (float)(1.0 - w1) : 0.0f);
            *(f32x4*)(wdense + (size_t)row * 4) = wv;
            int el = e1 < e2 ? e1 : e2;
            int eh = e1 < e2 ? e2 : e1;
            int pidx = (el == 0) ? (eh - 1) : ((el == 1) ? (eh + 1) : 5);
            atomicAdd(&shist[pidx], 1u);
            atomicAdd(&scnt[e1], 1u);
            atomicAdd(&scnt[e2], 1u);
        }
    }
    __syncthreads();
    if (tid < 4) atomicAdd(&ctr[tid], scnt[tid]);
    if (tid < 6) atomicAdd(&ctr[4 + tid], shist[tid]);
}

// ---------- offsets: 32-aligned bucket bases, zero cursors, fill padding slots
__global__ void offsets_kernel(unsigned int* __restrict__ ctr, int* __restrict__ perm) {
    __shared__ int sb[7], sh[6];
    int t = threadIdx.x;
    if (t == 0) {
        int base = 0;
        for (int p = 0; p < 6; ++p) {
            sb[p] = base;
            sh[p] = (int)ctr[4 + p];
            base += (sh[p] + 31) & ~31;
        }
        sb[6] = base;
        for (int p = 0; p < 7; ++p) ctr[16 + p] = (unsigned int)sb[p];
    }
    if (t < 6) ctr[10 + t] = 0u;
    __syncthreads();
    for (int p = 0; p < 6; ++p)
        for (int s = sb[p] + sh[p] + t; s < sb[p + 1]; s += 64)
            perm[s] = -1;
}

// ---------- scatter: two-level (LDS histogram -> one range-reserve atomic per bucket per block)
__global__ __launch_bounds__(256) void scatter_kernel(const float* __restrict__ wdense,
                                                      unsigned int* __restrict__ ctr,
                                                      int* __restrict__ perm) {
    __shared__ unsigned int lcnt[6];
    __shared__ unsigned int lbase[6];
    int tid = threadIdx.x;
    if (tid < 6) lcnt[tid] = 0u;
    __syncthreads();
    int r = blockIdx.x * 256 + tid;
    f32x4 w = *(const f32x4*)(wdense + (size_t)r * 4);
    int el = -1, eh = -1;
#pragma unroll
    for (int e = 0; e < 4; ++e)
        if (w[e] != 0.0f) { if (el < 0) el = e; else eh = e; }
    int pidx = (el == 0) ? (eh - 1) : ((el == 1) ? (eh + 1) : 5);
    unsigned int local = atomicAdd(&lcnt[pidx], 1u);
    __syncthreads();
    if (tid < 6) lbase[tid] = atomicAdd(&ctr[10 + tid], lcnt[tid]);
    __syncthreads();
    perm[ctr[16 + pidx] + lbase[pidx] + local] = r;
}

// ---------- fused 2-expert FFN + combine + residual + LayerNorm
// 32-row tile, 8 waves (512 thr); wave w owns output cols [w*32, w*32+32).
// Weights staged to LDS in 16KB k-stripes (256 cols x 32 k) via global_load_lds,
// double-buffered, counted-vmcnt pipeline, raw s_barrier (no mid-loop full drain).
__global__ __launch_bounds__(512, 4) void ffn_kernel(const float* __restrict__ z,
    const unsigned short* __restrict__ W1t, const unsigned short* __restrict__ W2t,
    const float* __restrict__ b1, const float* __restrict__ b2,
    const float* __restrict__ wdense, const float* __restrict__ ln_g,
    const float* __restrict__ ln_b, const unsigned int* __restrict__ ctr,
    const int* __restrict__ perm, float* __restrict__ y) {
    __shared__ char zls[16384];       // Z tile bf16 (32 x 256), 16B-slot XOR swizzle
    __shared__ char h1s[16384];       // H1 tile bf16, same swizzle
    __shared__ char wlds[32768];      // 2 x 16KB weight stripe buffers (linear chunks)
    __shared__ int ridx_s[32];
    __shared__ float wa_s[32], wb_s[32];
    __shared__ float ps[32][8], pq[32][8];

    int slot0 = blockIdx.x * 32;
    int total = (int)ctr[22];
    if (slot0 >= total) return;
    int p = 0;
#pragma unroll
    for (int q = 1; q < 6; ++q) if (slot0 >= (int)ctr[16 + q]) p = q;
    int ea = (p < 3) ? 0 : ((p < 5) ? 1 : 2);
    int eb = (p < 3) ? (p + 1) : ((p < 5) ? (p - 1) : 3);

    int tid = threadIdx.x;
    int lane = tid & 63, wv = tid >> 6;
    int ln15 = lane & 15, lhi = lane >> 4;
    int nbase = wv * 32;
    int swzA = ln15 << 5;

    const unsigned short* w1pa = W1t + (ea << 16);
    const unsigned short* w2pa = W2t + (ea << 16);
    const unsigned short* w1pb = W1t + (eb << 16);
    const unsigned short* w2pb = W2t + (eb << 16);

    if (tid < 32) {
        int g = perm[slot0 + tid];
        ridx_s[tid] = g;
        int g2 = (g < 0) ? 0 : g;
        wa_s[tid] = wdense[(size_t)g2 * 4 + ea];
        wb_s[tid] = wdense[(size_t)g2 * 4 + eb];
    }
    // b1 fragments into registers (keeps pipeline-phase vmem = stage loads only)
    f32x4 b1a[2], b1b[2];
#pragma unroll
    for (int fm = 0; fm < 2; ++fm) {
        int h0 = nbase + fm * 16 + lhi * 4;
        b1a[fm] = *(const f32x4*)(b1 + (ea << 8) + h0);
        b1b[fm] = *(const f32x4*)(b1 + (eb << 8) + h0);
    }
    __syncthreads();   // ridx_s visible for the gather below

    // gather + stage Z -> bf16 swizzled (2 iters x 512 thr x 8 elems = 32x256)
#pragma unroll
    for (int it = 0; it < 2; ++it) {
        int idx = it * 512 + tid;
        int r = idx >> 5, c8 = (idx & 31) << 3;
        int g = ridx_s[r]; if (g < 0) g = 0;
        f32x4 v0 = *(const f32x4*)(z + (size_t)g * 256 + c8);
        f32x4 v1 = *(const f32x4*)(z + (size_t)g * 256 + c8 + 4);
        u16x8 hv;
        hv[0] = f2bf(v0[0]); hv[1] = f2bf(v0[1]); hv[2] = f2bf(v0[2]); hv[3] = f2bf(v0[3]);
        hv[4] = f2bf(v1[0]); hv[5] = f2bf(v1[1]); hv[6] = f2bf(v1[2]); hv[7] = f2bf(v1[3]);
        *(u16x8*)(&zls[(r * 512 + c8 * 2) ^ SWZ(r)]) = hv;
    }
    VMCNT0;            // retire all ordinary vmem: in-loop vmcnt counts stage loads only

    // stage stripe sn (0..31): gemm = sn>>3 {G1a,G2a,G1b,G2b}, tn = sn&7 (k-stripe),
    // buf = sn&1. Stripe = 256 cols x 32 k bf16 = 16KB, linear chunks C = col*4 + ksub.
    auto stage = [&](int sn) {
        int gsel = sn >> 3;
        const unsigned short* g0 = (gsel == 0) ? w1pa : (gsel == 1) ? w2pa
                                 : (gsel == 2) ? w1pb : w2pb;
        int tn = sn & 7, wb = sn & 1;
#pragma unroll
        for (int it = 0; it < 2; ++it) {
            int C = it * 512 + tid;          // 0..1023
            int c = C >> 2, u = C & 3;
            gload_lds16(g0 + c * 256 + tn * 32 + u * 8, &wlds[wb * 16384 + C * 16]);
        }
    };

    f32x4 acc[2][2], acc1[2][2];
#pragma unroll
    for (int i = 0; i < 2; ++i)
#pragma unroll
        for (int j = 0; j < 2; ++j) acc[i][j] = (f32x4)0.0f;

    auto epi = [&](const f32x4* b1f, const float* wsel) {
#pragma unroll
        for (int fm = 0; fm < 2; ++fm) {
            int h0 = nbase + fm * 16 + lhi * 4;
#pragma unroll
            for (int fn = 0; fn < 2; ++fn) {
                int row = fn * 16 + ln15;
                float w = wsel[row];
                u16x4 hv;
#pragma unroll
                for (int i = 0; i < 4; ++i)
                    hv[i] = f2bf(gelu_f(acc1[fm][fn][i] + b1f[fm][i]) * w);
                *(u16x4*)(&h1s[(row * 512 + h0 * 2) ^ swzA]) = hv;
            }
        }
    };

    stage(0);
    stage(1);
    LGK0;              // zls/wa/wb ds_writes drained before first barrier

    for (int st = 0; st < 32; ++st) {
        if (st < 31) { VMCNT2; } else { VMCNT0; }
        BARRAW();
        SCHED0();
        int gsel = st >> 3;
        int tn = st & 7, wb = st & 1;
        bool isG1 = (gsel & 1) == 0;
        const char* wbase = &wlds[wb * 16384];
        const char* bsrc = isG1 ? zls : h1s;
        if (isG1 && tn == 0) {
#pragma unroll
            for (int i = 0; i < 2; ++i)
#pragma unroll
                for (int j = 0; j < 2; ++j) acc1[i][j] = (f32x4)0.0f;
        }
        short8 aw[2], bv[2];
#pragma unroll
        for (int fm = 0; fm < 2; ++fm) {
            int c = nbase + fm * 16 + ln15;
            aw[fm] = *(const short8*)(wbase + c * 64 + lhi * 16);
        }
        int kb = tn * 64 + lhi * 16;
#pragma unroll
        for (int fn = 0; fn < 2; ++fn)
            bv[fn] = *(const short8*)(bsrc + (((fn * 16 + ln15) * 512 + kb) ^ swzA));
        __builtin_amdgcn_s_setprio(1);
        if (isG1) {
#pragma unroll
            for (int fm = 0; fm < 2; ++fm)
#pragma unroll
                for (int fn = 0; fn < 2; ++fn)
                    acc1[fm][fn] = MFMA16(aw[fm], bv[fn], acc1[fm][fn]);
        } else {
#pragma unroll
            for (int fm = 0; fm < 2; ++fm)
#pragma unroll
                for (int fn = 0; fn < 2; ++fn)
                    acc[fm][fn] = MFMA16(aw[fm], bv[fn], acc[fm][fn]);
        }
        __builtin_amdgcn_s_setprio(0);
        if (st == 7)  epi(b1a, wa_s);
        if (st == 23) epi(b1b, wb_s);
        LGK0;          // h1s writes / ds reads drained before buffer reuse
        BARRAW();
        SCHED0();
        if (st < 30) stage(st + 2);
    }

    // fold biases + residual (bf16 z from LDS); per-row partial sums for LN
    float sA[2] = {0.0f, 0.0f};
    float sB[2] = {0.0f, 0.0f};
#pragma unroll
    for (int fm = 0; fm < 2; ++fm) {
        int d0 = nbase + fm * 16 + lhi * 4;
        f32x4 ba = *(const f32x4*)(b2 + (ea << 8) + d0);
        f32x4 bb = *(const f32x4*)(b2 + (eb << 8) + d0);
#pragma unroll
        for (int fn = 0; fn < 2; ++fn) {
            int row = fn * 16 + ln15;
            float wa = wa_s[row], wb = wb_s[row];
            u16x4 zr = *(const u16x4*)(&zls[(row * 512 + d0 * 2) ^ swzA]);
#pragma unroll
            for (int i = 0; i < 4; ++i) {
                float x = acc[fm][fn][i] + wa * ba[i] + wb * bb[i] + bf2f(zr[i]);
                acc[fm][fn][i] = x;
                sA[fn] += x;
                sB[fn] += x * x;
            }
        }
    }
#pragma unroll
    for (int fn = 0; fn < 2; ++fn) {
        sA[fn] += __shfl_xor(sA[fn], 16, 64);
        sA[fn] += __shfl_xor(sA[fn], 32, 64);
        sB[fn] += __shfl_xor(sB[fn], 16, 64);
        sB[fn] += __shfl_xor(sB[fn], 32, 64);
    }
    if (lhi < 2) {
        int row = lhi * 16 + ln15;     // lane group lhi contributes fn = lhi
        ps[row][wv] = (lhi == 0) ? sA[0] : sA[1];
        pq[row][wv] = (lhi == 0) ? sB[0] : sB[1];
    }
    LGK0;
    BARRAW();
    SCHED0();

    float mu[2], rs[2];
#pragma unroll
    for (int fn = 0; fn < 2; ++fn) {
        int row = fn * 16 + ln15;
        f32x4 a4 = *(const f32x4*)(&ps[row][0]);
        f32x4 a5 = *(const f32x4*)(&ps[row][4]);
        f32x4 b4 = *(const f32x4*)(&pq[row][0]);
        f32x4 b5 = *(const f32x4*)(&pq[row][4]);
        float s = (a4[0] + a4[1] + a4[2] + a4[3]) + (a5[0] + a5[1] + a5[2] + a5[3]);
        float q = (b4[0] + b4[1] + b4[2] + b4[3]) + (b5[0] + b5[1] + b5[2] + b5[3]);
        float m = s * (1.0f / 256.0f);
        float var = q * (1.0f / 256.0f) - m * m;
        mu[fn] = m;
        rs[fn] = rsqrtf(var + 1e-5f);
    }
#pragma unroll
    for (int fm = 0; fm < 2; ++fm) {
        int d0 = nbase + fm * 16 + lhi * 4;
        f32x4 gm = *(const f32x4*)(ln_g + d0);
        f32x4 bt = *(const f32x4*)(ln_b + d0);
#pragma unroll
        for (int fn = 0; fn < 2; ++fn) {
            int row = fn * 16 + ln15;
            int g = ridx_s[row];
            if (g >= 0) {
                f32x4 yv;
#pragma unroll
                for (int i = 0; i < 4; ++i)
                    yv[i] = gm[i] * ((acc[fm][fn][i] - mu[fn]) * rs[fn]) + bt[i];
                *(f32x4*)(y + (size_t)g * 256 + d0) = yv;
            }
        }
    }
}

// ---------- finalize: expert utilization (exact /2^18)
__global__ void final_kernel(const unsigned int* __restrict__ ctr, float* __restrict__ out) {
    int t = threadIdx.x;
    if (t < 4) out[(size_t)Bz * Dd + t] = (float)ctr[t] * (1.0f / 262144.0f);
}

extern "C" void kernel_launch(void* const* d_in, const int* in_sizes, int n_in,
                              void* d_out, int out_size, void* d_ws, size_t ws_size,
                              hipStream_t stream) {
    const float* z         = (const float*)d_in[0];
    const int*   ridx      = (const int*)d_in[1];
    const float* centroids = (const float*)d_in[2];
    const float* tau_raw   = (const float*)d_in[3];
    const float* W1        = (const float*)d_in[4];
    const float* b1        = (const float*)d_in[5];
    const float* W2        = (const float*)d_in[6];
    const float* b2        = (const float*)d_in[7];
    const float* lng       = (const float*)d_in[8];
    const float* lnb       = (const float*)d_in[9];
    float* out = (float*)d_out;

    unsigned short* W1t    = (unsigned short*)d_ws;                          // 512 KB
    unsigned short* W2t    = (unsigned short*)((char*)d_ws + 524288);        // 512 KB
    float*          wdense = (float*)((char*)d_ws + 1048576);                // 2 MB
    int*            perm   = (int*)((char*)d_ws + 3145728);                  // ~514 KB
    unsigned int*   ctr    = (unsigned int*)((char*)d_ws + 3672064);         // 96 B

    hipLaunchKernelGGL(prep_kernel, dim3(1024), dim3(256), 0, stream, W1, W2, W1t, W2t, ctr);
    hipLaunchKernelGGL(gate_kernel, dim3(2048), dim3(256), 0, stream, z, ridx, centroids, tau_raw, wdense, ctr);
    hipLaunchKernelGGL(offsets_kernel, dim3(1), dim3(64), 0, stream, ctr, perm);
    hipLaunchKernelGGL(scatter_kernel, dim3(512), dim3(256), 0, stream, wdense, ctr, perm);
    hipLaunchKernelGGL(ffn_kernel, dim3(4102), dim3(512), 0, stream, z, W1t, W2t, b1, b2, wdense, lng, lnb, ctr, perm, out);
    hipLaunchKernelGGL(final_kernel, dim3(1), dim3(64), 0, stream, ctr, out);
}

// Round 11
// 275.955 us; speedup vs baseline: 1.2602x; 1.2602x over previous
//
#include <hip/hip_runtime.h>
#include <hip/hip_bf16.h>
#include <math.h>

#define Bz 131072
#define Dd 256

typedef __attribute__((ext_vector_type(8))) short short8;
typedef __attribute__((ext_vector_type(4))) float f32x4;
typedef __attribute__((ext_vector_type(4))) unsigned short u16x4;
typedef __attribute__((ext_vector_type(8))) unsigned short u16x8;

__device__ __forceinline__ unsigned short f2bf(float f) {
    union { float f; unsigned int u; } v; v.f = f;
    unsigned int r = v.u + 0x7FFFu + ((v.u >> 16) & 1u);   // RNE
    return (unsigned short)(r >> 16);
}
__device__ __forceinline__ float bf2f(unsigned short h) {
    union { unsigned int u; float f; } v; v.u = ((unsigned int)h) << 16;
    return v.f;
}
// tanh-form gelu: 0.5x(1+tanh(0.7978845608(x+0.044715x^3))), tanh via v_exp_f32 (2^x)
__device__ __forceinline__ float gelu_f(float x) {
    float u = 0.7978845608028654f * x * (1.0f + 0.044715f * x * x);
    float ex = __builtin_amdgcn_exp2f(u * 2.8853900817779268f);  // 2*log2(e)
    float th = 1.0f - 2.0f * __builtin_amdgcn_rcpf(1.0f + ex);
    return 0.5f * x * (1.0f + th);
}

__device__ __forceinline__ void gload_lds16(const unsigned short* g, char* l) {
    __builtin_amdgcn_global_load_lds(
        (const __attribute__((address_space(1))) unsigned int*)g,
        (__attribute__((address_space(3))) unsigned int*)l, 16, 0, 0);
}

#define MFMA16(a, b, c) __builtin_amdgcn_mfma_f32_16x16x32_bf16(a, b, c, 0, 0, 0)
#define VMCNT2 asm volatile("s_waitcnt vmcnt(2)" ::: "memory")
#define VMCNT0 asm volatile("s_waitcnt vmcnt(0)" ::: "memory")
#define LGK0   asm volatile("s_waitcnt lgkmcnt(0)" ::: "memory")
#define BARRAW __builtin_amdgcn_s_barrier
#define SCHED0() __builtin_amdgcn_sched_barrier(0)

// ctr layout (uint): [0..3] expert counts, [4..9] pair hist, [10..15] cursors, [16..22] bases
// ---------- prep: bf16-convert + transpose weights into stripe-linear layout.
// Dest (per expert, per matrix): stripe tn (0..7) = 16KB = [u(0..3)][c(0..255)][j(0..7)]
// holding W[e][k = tn*32 + u*8 + j][c]. Staging then reads stripes linearly (coalesced)
// and LDS stripe reads are bank-conflict-free (col stride 16B).
__global__ __launch_bounds__(256) void prep_kernel(const float* __restrict__ W1,
                                                   const float* __restrict__ W2,
                                                   unsigned short* __restrict__ W1s,
                                                   unsigned short* __restrict__ W2s,
                                                   unsigned int* __restrict__ ctr) {
    __shared__ float tile[32][257];
    int bid = blockIdx.x;              // 64 blocks: mat(2) x e(4) x tn(8)
    int tid = threadIdx.x;
    if (bid == 0 && tid < 16) ctr[tid] = 0u;
    int mat = bid >> 5, e = (bid >> 3) & 3, tn = bid & 7;
    const float* src = (mat ? W2 : W1) + e * 65536;
    unsigned short* dst = (mat ? W2s : W1s) + e * 65536 + tn * 8192;
#pragma unroll 4
    for (int kk = 0; kk < 32; ++kk)
        tile[kk][tid] = src[(tn * 32 + kk) * 256 + tid];
    __syncthreads();
#pragma unroll 4
    for (int oo = 0; oo < 32; ++oo) {
        int o = oo * 256 + tid;        // 0..8191
        int u = o >> 11, c = (o >> 3) & 255, j = o & 7;
        dst[o] = f2bf(tile[u * 8 + j][c]);
    }
}

// ---------- gate: f64 distances -> top-2 -> weights + pair histogram + counts
__global__ __launch_bounds__(256) void gate_kernel(const float* __restrict__ z,
                                                   const int* __restrict__ ridx_p,
                                                   const float* __restrict__ centroids,
                                                   const float* __restrict__ tau_raw,
                                                   float* __restrict__ wdense,
                                                   unsigned int* __restrict__ ctr) {
    __shared__ unsigned int scnt[4];
    __shared__ unsigned int shist[6];
    int tid = threadIdx.x;
    if (tid < 4) scnt[tid] = 0u;
    if (tid < 6) shist[tid] = 0u;
    __syncthreads();
    int lane = tid & 63;
    int gwave = (blockIdx.x * 256 + tid) >> 6;         // 16 rows each
    int ridx = ridx_p[0];
    double tau = log1p(exp((double)tau_raw[ridx])) + 1e-6;
    const float* cb = centroids + (size_t)ridx * (4 * Dd);
    float c[4][4];
#pragma unroll
    for (int e = 0; e < 4; ++e) {
        f32x4 cv = *(const f32x4*)(cb + e * 256 + lane * 4);
#pragma unroll
        for (int j = 0; j < 4; ++j) c[e][j] = cv[j];
    }
    for (int rr = 0; rr < 16; ++rr) {
        int row = gwave * 16 + rr;
        f32x4 zv = *(const f32x4*)(z + (size_t)row * 256 + lane * 4);
        double d2[4] = {0.0, 0.0, 0.0, 0.0};
#pragma unroll
        for (int e = 0; e < 4; ++e)
#pragma unroll
            for (int j = 0; j < 4; ++j) {
                double df = (double)zv[j] - (double)c[e][j];
                d2[e] += df * df;
            }
#pragma unroll
        for (int m = 32; m >= 1; m >>= 1)
#pragma unroll
            for (int e = 0; e < 4; ++e) d2[e] += __shfl_xor(d2[e], m, 64);
        if (lane == 0) {
            int e1 = 0;
#pragma unroll
            for (int e = 1; e < 4; ++e) if (d2[e] < d2[e1]) e1 = e;
            int e2 = (e1 == 0) ? 1 : 0;
#pragma unroll
            for (int e = 0; e < 4; ++e)
                if (e != e1 && e != e2 && d2[e] < d2[e2]) e2 = e;
            double s1 = exp(-sqrt(d2[e1]) / tau);
            double s2 = exp(-sqrt(d2[e2]) / tau);
            double w1 = 1.0 / (1.0 + exp(s2 - s1));
            f32x4 wv;
#pragma unroll
            for (int j = 0; j < 4; ++j)
                wv[j] = (j == e1) ? (float)w1 : ((j == e2) ? (float)(1.0 - w1) : 0.0f);
            *(f32x4*)(wdense + (size_t)row * 4) = wv;
            int el = e1 < e2 ? e1 : e2;
            int eh = e1 < e2 ? e2 : e1;
            int pidx = (el == 0) ? (eh - 1) : ((el == 1) ? (eh + 1) : 5);
            atomicAdd(&shist[pidx], 1u);
            atomicAdd(&scnt[e1], 1u);
            atomicAdd(&scnt[e2], 1u);
        }
    }
    __syncthreads();
    if (tid < 4) atomicAdd(&ctr[tid], scnt[tid]);
    if (tid < 6) atomicAdd(&ctr[4 + tid], shist[tid]);
}

// ---------- offsets: 32-aligned bucket bases, zero cursors, fill padding slots
__global__ void offsets_kernel(unsigned int* __restrict__ ctr, int* __restrict__ perm) {
    __shared__ int sb[7], sh[6];
    int t = threadIdx.x;
    if (t == 0) {
        int base = 0;
        for (int p = 0; p < 6; ++p) {
            sb[p] = base;
            sh[p] = (int)ctr[4 + p];
            base += (sh[p] + 31) & ~31;
        }
        sb[6] = base;
        for (int p = 0; p < 7; ++p) ctr[16 + p] = (unsigned int)sb[p];
    }
    if (t < 6) ctr[10 + t] = 0u;
    __syncthreads();
    for (int p = 0; p < 6; ++p)
        for (int s = sb[p] + sh[p] + t; s < sb[p + 1]; s += 64)
            perm[s] = -1;
}

// ---------- scatter: two-level (LDS histogram -> one range-reserve atomic per bucket per block)
__global__ __launch_bounds__(256) void scatter_kernel(const float* __restrict__ wdense,
                                                      unsigned int* __restrict__ ctr,
                                                      int* __restrict__ perm) {
    __shared__ unsigned int lcnt[6];
    __shared__ unsigned int lbase[6];
    int tid = threadIdx.x;
    if (tid < 6) lcnt[tid] = 0u;
    __syncthreads();
    int r = blockIdx.x * 256 + tid;
    f32x4 w = *(const f32x4*)(wdense + (size_t)r * 4);
    int el = -1, eh = -1;
#pragma unroll
    for (int e = 0; e < 4; ++e)
        if (w[e] != 0.0f) { if (el < 0) el = e; else eh = e; }
    int pidx = (el == 0) ? (eh - 1) : ((el == 1) ? (eh + 1) : 5);
    unsigned int local = atomicAdd(&lcnt[pidx], 1u);
    __syncthreads();
    if (tid < 6) lbase[tid] = atomicAdd(&ctr[10 + tid], lcnt[tid]);
    __syncthreads();
    perm[ctr[16 + pidx] + lbase[pidx] + local] = r;
}

// ---------- fused 2-expert FFN + combine + residual + LayerNorm
// 32-row tile, 8 waves (512 thr); wave w owns output cols [w*32, w*32+32).
// Weights: 32 stripe-linear 16KB stages (identity-coalesced global_load_lds),
// double-buffered, counted vmcnt(2), raw barriers, fully unrolled stripe loop.
// LDS map (one block): [0,32K) wlds 2 bufs | [32K,48K) zls | [48K,64K) h1s.
// zls/h1s swizzle: 16B slot s at row r -> s ^ (r&7)  (bv reads 2-way max).
// wlds stripe: [u(=lhi)][c][j] -> aw read col-stride 16B (bank-free).
__global__ __launch_bounds__(512, 4) void ffn_kernel(const float* __restrict__ z,
    const unsigned short* __restrict__ W1s, const unsigned short* __restrict__ W2s,
    const float* __restrict__ b1, const float* __restrict__ b2,
    const float* __restrict__ wdense, const float* __restrict__ ln_g,
    const float* __restrict__ ln_b, const unsigned int* __restrict__ ctr,
    const int* __restrict__ perm, float* __restrict__ y) {
    __shared__ char lds[65536];
    __shared__ int ridx_s[32];
    __shared__ float wa_s[32], wb_s[32];
    __shared__ float ps[32][8], pq[32][8];
    char* wlds = lds;                  // 2 x 16KB
    char* zls  = lds + 32768;          // 16KB
    char* h1s  = lds + 49152;          // 16KB

    int slot0 = blockIdx.x * 32;
    int total = (int)ctr[22];
    if (slot0 >= total) return;
    int p = 0;
#pragma unroll
    for (int q = 1; q < 6; ++q) if (slot0 >= (int)ctr[16 + q]) p = q;
    int ea = (p < 3) ? 0 : ((p < 5) ? 1 : 2);
    int eb = (p < 3) ? (p + 1) : ((p < 5) ? (p - 1) : 3);

    int tid = threadIdx.x;
    int lane = tid & 63, wv = tid >> 6;
    int ln15 = lane & 15, lhi = lane >> 4;
    int l7 = ln15 & 7;
    int nbase = wv * 32;

    const unsigned short* g1a = W1s + (ea << 16);
    const unsigned short* g2a = W2s + (ea << 16);
    const unsigned short* g1b = W1s + (eb << 16);
    const unsigned short* g2b = W2s + (eb << 16);

    if (tid < 32) {
        int g = perm[slot0 + tid];
        ridx_s[tid] = g;
        int g2 = (g < 0) ? 0 : g;
        wa_s[tid] = wdense[(size_t)g2 * 4 + ea];
        wb_s[tid] = wdense[(size_t)g2 * 4 + eb];
    }
    // b1 fragments into registers (pipeline-phase vmem = stage loads only)
    f32x4 b1a[2], b1b[2];
#pragma unroll
    for (int fm = 0; fm < 2; ++fm) {
        int h0 = nbase + fm * 16 + lhi * 4;
        b1a[fm] = *(const f32x4*)(b1 + (ea << 8) + h0);
        b1b[fm] = *(const f32x4*)(b1 + (eb << 8) + h0);
    }
    __syncthreads();   // ridx_s visible for the gather below

    // gather + stage Z -> bf16, slot-XOR swizzle (2 iters x 512 thr x 16B)
#pragma unroll
    for (int it = 0; it < 2; ++it) {
        int idx = it * 512 + tid;
        int r = idx >> 5, sl = idx & 31;
        int g = ridx_s[r]; if (g < 0) g = 0;
        f32x4 v0 = *(const f32x4*)(z + (size_t)g * 256 + sl * 8);
        f32x4 v1 = *(const f32x4*)(z + (size_t)g * 256 + sl * 8 + 4);
        u16x8 hv;
        hv[0] = f2bf(v0[0]); hv[1] = f2bf(v0[1]); hv[2] = f2bf(v0[2]); hv[3] = f2bf(v0[3]);
        hv[4] = f2bf(v1[0]); hv[5] = f2bf(v1[1]); hv[6] = f2bf(v1[2]); hv[7] = f2bf(v1[3]);
        *(u16x8*)(&zls[r * 512 + ((sl ^ (r & 7)) << 4)]) = hv;
    }
    VMCNT0;            // retire ordinary vmem: in-loop vmcnt counts stage loads only

    // per-thread invariant offsets
    int Lbase = wv * 64 + lane;                 // staging chunk index base (it adds 512)
    int awc0 = lhi * 4096 + (nbase + ln15) * 16;        // fm=0
    int awc1 = awc0 + 256;                               // fm=1 (+16 cols * 16B)
    int bro0 = (ln15) * 512;                             // fn=0 row offset
    int bro1 = (16 + ln15) * 512;                        // fn=1

    f32x4 acc[2][2], acc1[2][2];
#pragma unroll
    for (int i = 0; i < 2; ++i)
#pragma unroll
        for (int j = 0; j < 2; ++j) acc[i][j] = (f32x4)0.0f;

    auto epi = [&](const f32x4* b1f, const float* wsel) {
#pragma unroll
        for (int fm = 0; fm < 2; ++fm) {
            int h0 = nbase + fm * 16 + lhi * 4;
            int hsl = (h0 >> 3) ^ 0;  // slot of h0 (8 cols/slot -> 4-col write = half slot)
#pragma unroll
            for (int fn = 0; fn < 2; ++fn) {
                int row = fn * 16 + ln15;
                float w = wsel[row];
                u16x4 hv;
#pragma unroll
                for (int i = 0; i < 4; ++i)
                    hv[i] = f2bf(gelu_f(acc1[fm][fn][i] + b1f[fm][i]) * w);
                *(u16x4*)(&h1s[row * 512 + (((hsl) ^ (row & 7)) << 4) + (h0 & 7) * 2]) = hv;
            }
        }
    };

    // stage stripe sn (0..31) into buf sn&1: identity-linear copy of a 16KB stripe
    auto stage = [&](int sn) {
        const unsigned short* g0 = ((sn >> 3) == 0) ? g1a : ((sn >> 3) == 1) ? g2a
                                 : ((sn >> 3) == 2) ? g1b : g2b;
        g0 += (sn & 7) * 8192;
        char* d = &wlds[(sn & 1) * 16384];
        gload_lds16(g0 + Lbase * 8, d + Lbase * 16);
        gload_lds16(g0 + (Lbase + 512) * 8, d + (Lbase + 512) * 16);
    };

    stage(0);
    stage(1);
    LGK0;              // zls ds_writes drained before first barrier

#pragma unroll
    for (int st = 0; st < 32; ++st) {
        if (st < 31) { VMCNT2; } else { VMCNT0; }
        BARRAW();
        SCHED0();
        const int tn = st & 7;
        const int wboff = (st & 1) * 16384;
        const bool isG1 = ((st >> 3) & 1) == 0;
        const int bsoff = isG1 ? 32768 : 49152;   // zls : h1s
        if (isG1 && tn == 0) {
#pragma unroll
            for (int i = 0; i < 2; ++i)
#pragma unroll
                for (int j = 0; j < 2; ++j) acc1[i][j] = (f32x4)0.0f;
        }
        short8 aw0 = *(const short8*)(&lds[wboff + awc0]);
        short8 aw1 = *(const short8*)(&lds[wboff + awc1]);
        int sl = ((tn * 4 + lhi) ^ l7) << 4;
        short8 bv0 = *(const short8*)(&lds[bsoff + bro0 + sl]);
        short8 bv1 = *(const short8*)(&lds[bsoff + bro1 + sl]);
        __builtin_amdgcn_s_setprio(1);
        if (isG1) {
            acc1[0][0] = MFMA16(aw0, bv0, acc1[0][0]);
            acc1[0][1] = MFMA16(aw0, bv1, acc1[0][1]);
            acc1[1][0] = MFMA16(aw1, bv0, acc1[1][0]);
            acc1[1][1] = MFMA16(aw1, bv1, acc1[1][1]);
        } else {
            acc[0][0] = MFMA16(aw0, bv0, acc[0][0]);
            acc[0][1] = MFMA16(aw0, bv1, acc[0][1]);
            acc[1][0] = MFMA16(aw1, bv0, acc[1][0]);
            acc[1][1] = MFMA16(aw1, bv1, acc[1][1]);
        }
        __builtin_amdgcn_s_setprio(0);
        if (st == 7)  epi(b1a, wa_s);
        if (st == 23) epi(b1b, wb_s);
        LGK0;          // my ds ops drained before buffer reuse barrier
        BARRAW();
        SCHED0();
        if (st < 30) stage(st + 2);
    }

    // fold biases + residual (bf16 z from LDS); per-row partial sums for LN
    float sA[2] = {0.0f, 0.0f};
    float sB[2] = {0.0f, 0.0f};
#pragma unroll
    for (int fm = 0; fm < 2; ++fm) {
        int d0 = nbase + fm * 16 + lhi * 4;
        int dsl = d0 >> 3, db = (d0 & 7) * 2;
        f32x4 ba = *(const f32x4*)(b2 + (ea << 8) + d0);
        f32x4 bb = *(const f32x4*)(b2 + (eb << 8) + d0);
#pragma unroll
        for (int fn = 0; fn < 2; ++fn) {
            int row = fn * 16 + ln15;
            float wa = wa_s[row], wb = wb_s[row];
            u16x4 zr = *(const u16x4*)(&zls[row * 512 + ((dsl ^ (row & 7)) << 4) + db]);
#pragma unroll
            for (int i = 0; i < 4; ++i) {
                float x = acc[fm][fn][i] + wa * ba[i] + wb * bb[i] + bf2f(zr[i]);
                acc[fm][fn][i] = x;
                sA[fn] += x;
                sB[fn] += x * x;
            }
        }
    }
#pragma unroll
    for (int fn = 0; fn < 2; ++fn) {
        sA[fn] += __shfl_xor(sA[fn], 16, 64);
        sA[fn] += __shfl_xor(sA[fn], 32, 64);
        sB[fn] += __shfl_xor(sB[fn], 16, 64);
        sB[fn] += __shfl_xor(sB[fn], 32, 64);
    }
    if (lhi < 2) {
        int row = lhi * 16 + ln15;     // lane group lhi contributes fn = lhi
        ps[row][wv] = (lhi == 0) ? sA[0] : sA[1];
        pq[row][wv] = (lhi == 0) ? sB[0] : sB[1];
    }
    LGK0;
    BARRAW();
    SCHED0();

    float mu[2], rs[2];
#pragma unroll
    for (int fn = 0; fn < 2; ++fn) {
        int row = fn * 16 + ln15;
        f32x4 a4 = *(const f32x4*)(&ps[row][0]);
        f32x4 a5 = *(const f32x4*)(&ps[row][4]);
        f32x4 b4 = *(const f32x4*)(&pq[row][0]);
        f32x4 b5 = *(const f32x4*)(&pq[row][4]);
        float s = (a4[0] + a4[1] + a4[2] + a4[3]) + (a5[0] + a5[1] + a5[2] + a5[3]);
        float q = (b4[0] + b4[1] + b4[2] + b4[3]) + (b5[0] + b5[1] + b5[2] + b5[3]);
        float m = s * (1.0f / 256.0f);
        float var = q * (1.0f / 256.0f) - m * m;
        mu[fn] = m;
        rs[fn] = rsqrtf(var + 1e-5f);
    }
#pragma unroll
    for (int fm = 0; fm < 2; ++fm) {
        int d0 = nbase + fm * 16 + lhi * 4;
        f32x4 gm = *(const f32x4*)(ln_g + d0);
        f32x4 bt = *(const f32x4*)(ln_b + d0);
#pragma unroll
        for (int fn = 0; fn < 2; ++fn) {
            int row = fn * 16 + ln15;
            int g = ridx_s[row];
            if (g >= 0) {
                f32x4 yv;
#pragma unroll
                for (int i = 0; i < 4; ++i)
                    yv[i] = gm[i] * ((acc[fm][fn][i] - mu[fn]) * rs[fn]) + bt[i];
                *(f32x4*)(y + (size_t)g * 256 + d0) = yv;
            }
        }
    }
}

// ---------- finalize: expert utilization (exact /2^18)
__global__ void final_kernel(const unsigned int* __restrict__ ctr, float* __restrict__ out) {
    int t = threadIdx.x;
    if (t < 4) out[(size_t)Bz * Dd + t] = (float)ctr[t] * (1.0f / 262144.0f);
}

extern "C" void kernel_launch(void* const* d_in, const int* in_sizes, int n_in,
                              void* d_out, int out_size, void* d_ws, size_t ws_size,
                              hipStream_t stream) {
    const float* z         = (const float*)d_in[0];
    const int*   ridx      = (const int*)d_in[1];
    const float* centroids = (const float*)d_in[2];
    const float* tau_raw   = (const float*)d_in[3];
    const float* W1        = (const float*)d_in[4];
    const float* b1        = (const float*)d_in[5];
    const float* W2        = (const float*)d_in[6];
    const float* b2        = (const float*)d_in[7];
    const float* lng       = (const float*)d_in[8];
    const float* lnb       = (const float*)d_in[9];
    float* out = (float*)d_out;

    unsigned short* W1s    = (unsigned short*)d_ws;                          // 512 KB
    unsigned short* W2s    = (unsigned short*)((char*)d_ws + 524288);        // 512 KB
    float*          wdense = (float*)((char*)d_ws + 1048576);                // 2 MB
    int*            perm   = (int*)((char*)d_ws + 3145728);                  // ~514 KB
    unsigned int*   ctr    = (unsigned int*)((char*)d_ws + 3672064);         // 96 B

    hipLaunchKernelGGL(prep_kernel, dim3(64), dim3(256), 0, stream, W1, W2, W1s, W2s, ctr);
    hipLaunchKernelGGL(gate_kernel, dim3(2048), dim3(256), 0, stream, z, ridx, centroids, tau_raw, wdense, ctr);
    hipLaunchKernelGGL(offsets_kernel, dim3(1), dim3(64), 0, stream, ctr, perm);
    hipLaunchKernelGGL(scatter_kernel, dim3(512), dim3(256), 0, stream, wdense, ctr, perm);
    hipLaunchKernelGGL(ffn_kernel, dim3(4102), dim3(512), 0, stream, z, W1s, W2s, b1, b2, wdense, lng, lnb, ctr, perm, out);
    hipLaunchKernelGGL(final_kernel, dim3(1), dim3(64), 0, stream, ctr, out);
}

// Round 12
// 246.654 us; speedup vs baseline: 1.4099x; 1.1188x over previous
//
#include <hip/hip_runtime.h>
#include <hip/hip_bf16.h>
#include <math.h>

#define Bz 131072
#define Dd 256

typedef __attribute__((ext_vector_type(8))) short short8;
typedef __attribute__((ext_vector_type(4))) float f32x4;
typedef __attribute__((ext_vector_type(4))) unsigned short u16x4;
typedef __attribute__((ext_vector_type(8))) unsigned short u16x8;

__device__ __forceinline__ unsigned short f2bf(float f) {
    union { float f; unsigned int u; } v; v.f = f;
    unsigned int r = v.u + 0x7FFFu + ((v.u >> 16) & 1u);   // RNE
    return (unsigned short)(r >> 16);
}
__device__ __forceinline__ float bf2f(unsigned short h) {
    union { unsigned int u; float f; } v; v.u = ((unsigned int)h) << 16;
    return v.f;
}
// tanh-form gelu: 0.5x(1+tanh(0.7978845608(x+0.044715x^3))), tanh via v_exp_f32 (2^x)
__device__ __forceinline__ float gelu_f(float x) {
    float u = 0.7978845608028654f * x * (1.0f + 0.044715f * x * x);
    float ex = __builtin_amdgcn_exp2f(u * 2.8853900817779268f);  // 2*log2(e)
    float th = 1.0f - 2.0f * __builtin_amdgcn_rcpf(1.0f + ex);
    return 0.5f * x * (1.0f + th);
}

#define MFMA16(a, b, c) __builtin_amdgcn_mfma_f32_16x16x32_bf16(a, b, c, 0, 0, 0)

// ctr layout (uint): [0..3] expert counts, [4..9] pair hist, [10..15] cursors, [16..22] bases
// ---------- prep: bf16-convert + transpose weights into stripe-linear layout.
// Per expert, per matrix: stripe tn (0..7) = 16KB = [u(0..3)][c(0..255)][j(0..7)]
// holding W[e][k = tn*32 + u*8 + j][c]. A wave's per-stripe fragment loads are
// 256-512B contiguous segments (coalesced, full cache lines).
__global__ __launch_bounds__(256) void prep_kernel(const float* __restrict__ W1,
                                                   const float* __restrict__ W2,
                                                   unsigned short* __restrict__ W1s,
                                                   unsigned short* __restrict__ W2s,
                                                   unsigned int* __restrict__ ctr) {
    __shared__ float tile[32][257];
    int bid = blockIdx.x;              // 64 blocks: mat(2) x e(4) x tn(8)
    int tid = threadIdx.x;
    if (bid == 0 && tid < 16) ctr[tid] = 0u;
    int mat = bid >> 5, e = (bid >> 3) & 3, tn = bid & 7;
    const float* src = (mat ? W2 : W1) + e * 65536;
    unsigned short* dst = (mat ? W2s : W1s) + e * 65536 + tn * 8192;
#pragma unroll 4
    for (int kk = 0; kk < 32; ++kk)
        tile[kk][tid] = src[(tn * 32 + kk) * 256 + tid];
    __syncthreads();
#pragma unroll 4
    for (int oo = 0; oo < 32; ++oo) {
        int o = oo * 256 + tid;        // 0..8191
        int u = o >> 11, c = (o >> 3) & 255, j = o & 7;
        dst[o] = f2bf(tile[u * 8 + j][c]);
    }
}

// ---------- gate: f64 distances -> top-2 -> weights + pair histogram + counts
__global__ __launch_bounds__(256) void gate_kernel(const float* __restrict__ z,
                                                   const int* __restrict__ ridx_p,
                                                   const float* __restrict__ centroids,
                                                   const float* __restrict__ tau_raw,
                                                   float* __restrict__ wdense,
                                                   unsigned int* __restrict__ ctr) {
    __shared__ unsigned int scnt[4];
    __shared__ unsigned int shist[6];
    int tid = threadIdx.x;
    if (tid < 4) scnt[tid] = 0u;
    if (tid < 6) shist[tid] = 0u;
    __syncthreads();
    int lane = tid & 63;
    int gwave = (blockIdx.x * 256 + tid) >> 6;         // 16 rows each
    int ridx = ridx_p[0];
    double tau = log1p(exp((double)tau_raw[ridx])) + 1e-6;
    const float* cb = centroids + (size_t)ridx * (4 * Dd);
    float c[4][4];
#pragma unroll
    for (int e = 0; e < 4; ++e) {
        f32x4 cv = *(const f32x4*)(cb + e * 256 + lane * 4);
#pragma unroll
        for (int j = 0; j < 4; ++j) c[e][j] = cv[j];
    }
    for (int rr = 0; rr < 16; ++rr) {
        int row = gwave * 16 + rr;
        f32x4 zv = *(const f32x4*)(z + (size_t)row * 256 + lane * 4);
        double d2[4] = {0.0, 0.0, 0.0, 0.0};
#pragma unroll
        for (int e = 0; e < 4; ++e)
#pragma unroll
            for (int j = 0; j < 4; ++j) {
                double df = (double)zv[j] - (double)c[e][j];
                d2[e] += df * df;
            }
#pragma unroll
        for (int m = 32; m >= 1; m >>= 1)
#pragma unroll
            for (int e = 0; e < 4; ++e) d2[e] += __shfl_xor(d2[e], m, 64);
        if (lane == 0) {
            int e1 = 0;
#pragma unroll
            for (int e = 1; e < 4; ++e) if (d2[e] < d2[e1]) e1 = e;
            int e2 = (e1 == 0) ? 1 : 0;
#pragma unroll
            for (int e = 0; e < 4; ++e)
                if (e != e1 && e != e2 && d2[e] < d2[e2]) e2 = e;
            double s1 = exp(-sqrt(d2[e1]) / tau);
            double s2 = exp(-sqrt(d2[e2]) / tau);
            double w1 = 1.0 / (1.0 + exp(s2 - s1));
            f32x4 wv;
#pragma unroll
            for (int j = 0; j < 4; ++j)
                wv[j] = (j == e1) ? (float)w1 : ((j == e2) ? (float)(1.0 - w1) : 0.0f);
            *(f32x4*)(wdense + (size_t)row * 4) = wv;
            int el = e1 < e2 ? e1 : e2;
            int eh = e1 < e2 ? e2 : e1;
            int pidx = (el == 0) ? (eh - 1) : ((el == 1) ? (eh + 1) : 5);
            atomicAdd(&shist[pidx], 1u);
            atomicAdd(&scnt[e1], 1u);
            atomicAdd(&scnt[e2], 1u);
        }
    }
    __syncthreads();
    if (tid < 4) atomicAdd(&ctr[tid], scnt[tid]);
    if (tid < 6) atomicAdd(&ctr[4 + tid], shist[tid]);
}

// ---------- offsets: 64-aligned bucket bases, zero cursors, fill padding slots
__global__ void offsets_kernel(unsigned int* __restrict__ ctr, int* __restrict__ perm) {
    __shared__ int sb[7], sh[6];
    int t = threadIdx.x;
    if (t == 0) {
        int base = 0;
        for (int p = 0; p < 6; ++p) {
            sb[p] = base;
            sh[p] = (int)ctr[4 + p];
            base += (sh[p] + 63) & ~63;
        }
        sb[6] = base;
        for (int p = 0; p < 7; ++p) ctr[16 + p] = (unsigned int)sb[p];
    }
    if (t < 6) ctr[10 + t] = 0u;
    __syncthreads();
    for (int p = 0; p < 6; ++p)
        for (int s = sb[p] + sh[p] + t; s < sb[p + 1]; s += 64)
            perm[s] = -1;
}

// ---------- scatter: two-level (LDS histogram -> one range-reserve atomic per bucket per block)
__global__ __launch_bounds__(256) void scatter_kernel(const float* __restrict__ wdense,
                                                      unsigned int* __restrict__ ctr,
                                                      int* __restrict__ perm) {
    __shared__ unsigned int lcnt[6];
    __shared__ unsigned int lbase[6];
    int tid = threadIdx.x;
    if (tid < 6) lcnt[tid] = 0u;
    __syncthreads();
    int r = blockIdx.x * 256 + tid;
    f32x4 w = *(const f32x4*)(wdense + (size_t)r * 4);
    int el = -1, eh = -1;
#pragma unroll
    for (int e = 0; e < 4; ++e)
        if (w[e] != 0.0f) { if (el < 0) el = e; else eh = e; }
    int pidx = (el == 0) ? (eh - 1) : ((el == 1) ? (eh + 1) : 5);
    unsigned int local = atomicAdd(&lcnt[pidx], 1u);
    __syncthreads();
    if (tid < 6) lbase[tid] = atomicAdd(&ctr[10 + tid], lcnt[tid]);
    __syncthreads();
    perm[ctr[16 + pidx] + lbase[pidx] + local] = r;
}

// ---------- fused 2-expert FFN + combine + residual + LayerNorm
// 64-row tile, 8 waves (512 thr); wave w owns output cols [w*32, w*32+32).
// Weights: per-wave global->VGPR fragment loads (stripe-linear layout, coalesced),
// distance-1 register prefetch inside each unrolled 8-stripe phase. NO weight LDS,
// NO per-stripe barriers: only 5 __syncthreads (zls ready + h1s handoffs + LN).
// zls/h1s (32KB each): 16B slot s at row r -> s ^ (r&7) (2-way max on b128 reads).
__global__ __launch_bounds__(512, 4) void ffn_kernel(const float* __restrict__ z,
    const unsigned short* __restrict__ W1s, const unsigned short* __restrict__ W2s,
    const float* __restrict__ b1, const float* __restrict__ b2,
    const float* __restrict__ wdense, const float* __restrict__ ln_g,
    const float* __restrict__ ln_b, const unsigned int* __restrict__ ctr,
    const int* __restrict__ perm, float* __restrict__ y) {
    __shared__ char zls[32768];        // Z tile bf16 (64 x 256), slot-XOR swizzle
    __shared__ char h1s[32768];        // H1 tile bf16, same swizzle
    __shared__ int ridx_s[64];
    __shared__ float wa_s[64], wb_s[64];
    __shared__ float ps[64][8], pq[64][8];

    int slot0 = blockIdx.x * 64;
    int total = (int)ctr[22];
    if (slot0 >= total) return;
    int p = 0;
#pragma unroll
    for (int q = 1; q < 6; ++q) if (slot0 >= (int)ctr[16 + q]) p = q;
    int ea = (p < 3) ? 0 : ((p < 5) ? 1 : 2);
    int eb = (p < 3) ? (p + 1) : ((p < 5) ? (p - 1) : 3);

    int tid = threadIdx.x;
    int lane = tid & 63, wv = tid >> 6;
    int ln15 = lane & 15, lhi = lane >> 4;
    int l7 = ln15 & 7;
    int nbase = wv * 32;

    const unsigned short* g1a = W1s + (ea << 16);
    const unsigned short* g2a = W2s + (ea << 16);
    const unsigned short* g1b = W1s + (eb << 16);
    const unsigned short* g2b = W2s + (eb << 16);

    if (tid < 64) {
        int g = perm[slot0 + tid];
        ridx_s[tid] = g;
        int g2 = (g < 0) ? 0 : g;
        wa_s[tid] = wdense[(size_t)g2 * 4 + ea];
        wb_s[tid] = wdense[(size_t)g2 * 4 + eb];
    }
    // b1 fragments into registers
    f32x4 b1a[2], b1b[2];
#pragma unroll
    for (int fm = 0; fm < 2; ++fm) {
        int h0 = nbase + fm * 16 + lhi * 4;
        b1a[fm] = *(const f32x4*)(b1 + (ea << 8) + h0);
        b1b[fm] = *(const f32x4*)(b1 + (eb << 8) + h0);
    }
    __syncthreads();   // ridx_s visible

    // gather + stage Z -> bf16, slot-XOR swizzle (4 iters x 512 thr x 16B = 64x512B)
#pragma unroll
    for (int it = 0; it < 4; ++it) {
        int idx = it * 512 + tid;
        int r = idx >> 5, sl = idx & 31;
        int g = ridx_s[r]; if (g < 0) g = 0;
        f32x4 v0 = *(const f32x4*)(z + (size_t)g * 256 + sl * 8);
        f32x4 v1 = *(const f32x4*)(z + (size_t)g * 256 + sl * 8 + 4);
        u16x8 hv;
        hv[0] = f2bf(v0[0]); hv[1] = f2bf(v0[1]); hv[2] = f2bf(v0[2]); hv[3] = f2bf(v0[3]);
        hv[4] = f2bf(v1[0]); hv[5] = f2bf(v1[1]); hv[6] = f2bf(v1[2]); hv[7] = f2bf(v1[3]);
        *(u16x8*)(&zls[r * 512 + ((sl ^ (r & 7)) << 4)]) = hv;
    }
    __syncthreads();   // zls ready

    // per-thread invariant weight-fragment offset (elements) within a stripe
    int wfo = lhi * 2048 + (nbase + ln15) * 8;     // fm=0 ; fm=1 adds 128

    f32x4 acc[2][4], acc1[2][4];
#pragma unroll
    for (int i = 0; i < 2; ++i)
#pragma unroll
        for (int j = 0; j < 4; ++j) acc[i][j] = (f32x4)0.0f;

    // one GEMM pass: 8 k-stripes, register-prefetched weights, LDS B operand
    auto gemm_phase = [&](const unsigned short* g0, const char* bsrc, f32x4 (&dst)[2][4]) {
        short8 awc0 = *(const short8*)(g0 + wfo);
        short8 awc1 = *(const short8*)(g0 + wfo + 128);
#pragma unroll
        for (int tn = 0; tn < 8; ++tn) {
            short8 awn0, awn1;
            if (tn < 7) {
                awn0 = *(const short8*)(g0 + (tn + 1) * 8192 + wfo);
                awn1 = *(const short8*)(g0 + (tn + 1) * 8192 + wfo + 128);
            }
            short8 bv[4];
#pragma unroll
            for (int fn = 0; fn < 4; ++fn) {
                int row = fn * 16 + ln15;
                bv[fn] = *(const short8*)(bsrc + row * 512 + (((tn * 4 + lhi) ^ l7) << 4));
            }
            __builtin_amdgcn_s_setprio(1);
#pragma unroll
            for (int fn = 0; fn < 4; ++fn) {
                dst[0][fn] = MFMA16(awc0, bv[fn], dst[0][fn]);
                dst[1][fn] = MFMA16(awc1, bv[fn], dst[1][fn]);
            }
            __builtin_amdgcn_s_setprio(0);
            if (tn < 7) { awc0 = awn0; awc1 = awn1; }
        }
    };

    auto epi = [&](const f32x4* b1f, const float* wsel) {
#pragma unroll
        for (int fm = 0; fm < 2; ++fm) {
            int h0 = nbase + fm * 16 + lhi * 4;
            int hsl = h0 >> 3, hb = (h0 & 7) * 2;
#pragma unroll
            for (int fn = 0; fn < 4; ++fn) {
                int row = fn * 16 + ln15;
                float w = wsel[row];
                u16x4 hv;
#pragma unroll
                for (int i = 0; i < 4; ++i)
                    hv[i] = f2bf(gelu_f(acc1[fm][fn][i] + b1f[fm][i]) * w);
                *(u16x4*)(&h1s[row * 512 + ((hsl ^ (row & 7)) << 4) + hb]) = hv;
            }
        }
    };

    // ---- expert A
#pragma unroll
    for (int i = 0; i < 2; ++i)
#pragma unroll
        for (int j = 0; j < 4; ++j) acc1[i][j] = (f32x4)0.0f;
    gemm_phase(g1a, zls, acc1);
    epi(b1a, wa_s);
    __syncthreads();                   // h1s(A) ready
    gemm_phase(g2a, h1s, acc);
    __syncthreads();                   // h1s(A) consumed
    // ---- expert B
#pragma unroll
    for (int i = 0; i < 2; ++i)
#pragma unroll
        for (int j = 0; j < 4; ++j) acc1[i][j] = (f32x4)0.0f;
    gemm_phase(g1b, zls, acc1);
    epi(b1b, wb_s);
    __syncthreads();                   // h1s(B) ready
    gemm_phase(g2b, h1s, acc);

    // fold biases + residual (bf16 z from LDS); per-row partial sums for LN
    float sA[4] = {0.0f, 0.0f, 0.0f, 0.0f};
    float sB[4] = {0.0f, 0.0f, 0.0f, 0.0f};
#pragma unroll
    for (int fm = 0; fm < 2; ++fm) {
        int d0 = nbase + fm * 16 + lhi * 4;
        int dsl = d0 >> 3, db = (d0 & 7) * 2;
        f32x4 ba = *(const f32x4*)(b2 + (ea << 8) + d0);
        f32x4 bb = *(const f32x4*)(b2 + (eb << 8) + d0);
#pragma unroll
        for (int fn = 0; fn < 4; ++fn) {
            int row = fn * 16 + ln15;
            float wa = wa_s[row], wb = wb_s[row];
            u16x4 zr = *(const u16x4*)(&zls[row * 512 + ((dsl ^ (row & 7)) << 4) + db]);
#pragma unroll
            for (int i = 0; i < 4; ++i) {
                float x = acc[fm][fn][i] + wa * ba[i] + wb * bb[i] + bf2f(zr[i]);
                acc[fm][fn][i] = x;
                sA[fn] += x;
                sB[fn] += x * x;
            }
        }
    }
#pragma unroll
    for (int fn = 0; fn < 4; ++fn) {
        sA[fn] += __shfl_xor(sA[fn], 16, 64);
        sA[fn] += __shfl_xor(sA[fn], 32, 64);
        sB[fn] += __shfl_xor(sB[fn], 16, 64);
        sB[fn] += __shfl_xor(sB[fn], 32, 64);
    }
    {
        float v1 = (lhi == 0) ? sA[0] : (lhi == 1) ? sA[1] : (lhi == 2) ? sA[2] : sA[3];
        float v2 = (lhi == 0) ? sB[0] : (lhi == 1) ? sB[1] : (lhi == 2) ? sB[2] : sB[3];
        int row = lhi * 16 + ln15;     // lane group lhi contributes fn = lhi
        ps[row][wv] = v1;
        pq[row][wv] = v2;
    }
    __syncthreads();

    float mu[4], rs[4];
#pragma unroll
    for (int fn = 0; fn < 4; ++fn) {
        int row = fn * 16 + ln15;
        f32x4 a4 = *(const f32x4*)(&ps[row][0]);
        f32x4 a5 = *(const f32x4*)(&ps[row][4]);
        f32x4 b4 = *(const f32x4*)(&pq[row][0]);
        f32x4 b5 = *(const f32x4*)(&pq[row][4]);
        float s = (a4[0] + a4[1] + a4[2] + a4[3]) + (a5[0] + a5[1] + a5[2] + a5[3]);
        float q = (b4[0] + b4[1] + b4[2] + b4[3]) + (b5[0] + b5[1] + b5[2] + b5[3]);
        float m = s * (1.0f / 256.0f);
        float var = q * (1.0f / 256.0f) - m * m;
        mu[fn] = m;
        rs[fn] = rsqrtf(var + 1e-5f);
    }
#pragma unroll
    for (int fm = 0; fm < 2; ++fm) {
        int d0 = nbase + fm * 16 + lhi * 4;
        f32x4 gm = *(const f32x4*)(ln_g + d0);
        f32x4 bt = *(const f32x4*)(ln_b + d0);
#pragma unroll
        for (int fn = 0; fn < 4; ++fn) {
            int row = fn * 16 + ln15;
            int g = ridx_s[row];
            if (g >= 0) {
                f32x4 yv;
#pragma unroll
                for (int i = 0; i < 4; ++i)
                    yv[i] = gm[i] * ((acc[fm][fn][i] - mu[fn]) * rs[fn]) + bt[i];
                *(f32x4*)(y + (size_t)g * 256 + d0) = yv;
            }
        }
    }
}

// ---------- finalize: expert utilization (exact /2^18)
__global__ void final_kernel(const unsigned int* __restrict__ ctr, float* __restrict__ out) {
    int t = threadIdx.x;
    if (t < 4) out[(size_t)Bz * Dd + t] = (float)ctr[t] * (1.0f / 262144.0f);
}

extern "C" void kernel_launch(void* const* d_in, const int* in_sizes, int n_in,
                              void* d_out, int out_size, void* d_ws, size_t ws_size,
                              hipStream_t stream) {
    const float* z         = (const float*)d_in[0];
    const int*   ridx      = (const int*)d_in[1];
    const float* centroids = (const float*)d_in[2];
    const float* tau_raw   = (const float*)d_in[3];
    const float* W1        = (const float*)d_in[4];
    const float* b1        = (const float*)d_in[5];
    const float* W2        = (const float*)d_in[6];
    const float* b2        = (const float*)d_in[7];
    const float* lng       = (const float*)d_in[8];
    const float* lnb       = (const float*)d_in[9];
    float* out = (float*)d_out;

    unsigned short* W1s    = (unsigned short*)d_ws;                          // 512 KB
    unsigned short* W2s    = (unsigned short*)((char*)d_ws + 524288);        // 512 KB
    float*          wdense = (float*)((char*)d_ws + 1048576);                // 2 MB
    int*            perm   = (int*)((char*)d_ws + 3145728);                  // ~514 KB
    unsigned int*   ctr    = (unsigned int*)((char*)d_ws + 3672064);         // 96 B

    hipLaunchKernelGGL(prep_kernel, dim3(64), dim3(256), 0, stream, W1, W2, W1s, W2s, ctr);
    hipLaunchKernelGGL(gate_kernel, dim3(2048), dim3(256), 0, stream, z, ridx, centroids, tau_raw, wdense, ctr);
    hipLaunchKernelGGL(offsets_kernel, dim3(1), dim3(64), 0, stream, ctr, perm);
    hipLaunchKernelGGL(scatter_kernel, dim3(512), dim3(256), 0, stream, wdense, ctr, perm);
    hipLaunchKernelGGL(ffn_kernel, dim3(2054), dim3(512), 0, stream, z, W1s, W2s, b1, b2, wdense, lng, lnb, ctr, perm, out);
    hipLaunchKernelGGL(final_kernel, dim3(1), dim3(64), 0, stream, ctr, out);
}